// Round 4
// baseline (85.731 us; speedup 1.0000x reference)
//
#include <hip/hip_runtime.h>
#include <hip/hip_bf16.h>

typedef __attribute__((ext_vector_type(4))) float f32x4;
typedef __attribute__((ext_vector_type(8))) short bf16x8;
typedef __attribute__((ext_vector_type(4))) short bf16x4;
typedef __attribute__((ext_vector_type(2))) unsigned int u32x2;

#define DEV static __device__ __forceinline__

constexpr float LOG2E  = 1.4426950408889634f;
constexpr float QSCALE = 0.17677669529663687f * LOG2E;  // hd^-0.5 * log2e

// ws layout (bytes)
constexpr size_t OFF_Q   = 0;                    // bf16 frag Q  (256 bh x 32 qg x 512)
constexpr size_t OFF_K   = (size_t)8  << 20;     // bf16 frag K  (256 bh x 32 tg x 512)
constexpr size_t OFF_V   = (size_t)16 << 20;     // bf16 frag V  (256 bh x 16 ug x 2 dh x 512), j-permuted
constexpr size_t OFF_RPB = (size_t)24 << 20;     // bf16 frag bias (4 h x 32 qg x 32 jc x 64 lane x 4)
constexpr size_t OFF_AO  = (size_t)27 << 20;     // bf16 head-major (bh, n, 32)
constexpr size_t OFF_POS = (size_t)35 << 20;     // f32  (3375, 4)
constexpr size_t OFF_WQ  = (size_t)36 << 20;     // bf16 (384, 128)
constexpr size_t OFF_WP  = (size_t)37 << 20;     // bf16 (128, 128)

DEV short f2b(float f) {
  union { __bf16 h; short s; } u;
  u.h = (__bf16)f;
  return u.s;
}
DEV float b2f(unsigned int u) {
  union { unsigned int u; float f; } x; x.u = u; return x.f;
}
DEV unsigned int pkbf(float a, float b) {
  union { __bf16 h; unsigned short s; } ua, ub;
  ua.h = (__bf16)a; ub.h = (__bf16)b;
  return (unsigned int)ua.s | ((unsigned int)ub.s << 16);
}

// ---------------- K0: DynamicPosBias MLP ----------------
DEV void ln_relu8(const float* v, const float* __restrict__ g,
                  const float* __restrict__ b, float* t) {
  float m = 0.f;
#pragma unroll
  for (int i = 0; i < 8; i++) m += v[i];
  m *= 0.125f;
  float var = 0.f;
#pragma unroll
  for (int i = 0; i < 8; i++) { float d = v[i] - m; var += d * d; }
  var *= 0.125f;
  float inv = 1.0f / sqrtf(var + 1e-5f);
#pragma unroll
  for (int i = 0; i < 8; i++) {
    float u = (v[i] - m) * inv * g[i] + b[i];
    t[i] = u > 0.f ? u : 0.f;
  }
}

DEV void mm8(const float* t, const float* __restrict__ w,
             const float* __restrict__ c, float* o) {
#pragma unroll
  for (int oo = 0; oo < 8; oo++) {
    float a = c[oo];
#pragma unroll
    for (int i = 0; i < 8; i++) a += t[i] * w[oo * 8 + i];
    o[oo] = a;
  }
}

__global__ void ca_posmlp(
    const float* __restrict__ pw, const float* __restrict__ pb,
    const float* __restrict__ g1, const float* __restrict__ b1,
    const float* __restrict__ w1, const float* __restrict__ c1,
    const float* __restrict__ g2, const float* __restrict__ b2,
    const float* __restrict__ w2, const float* __restrict__ c2,
    const float* __restrict__ g3, const float* __restrict__ b3,
    const float* __restrict__ w3, const float* __restrict__ c3,
    float* __restrict__ pos_out) {
  int r = blockIdx.x * 256 + threadIdx.x;
  if (r >= 3375) return;
  float x0 = (float)(r / 225 - 7);
  float x1 = (float)((r / 15) % 15 - 7);
  float x2 = (float)(r % 15 - 7);
  float v[8], t[8], u[8];
#pragma unroll
  for (int o = 0; o < 8; o++)
    v[o] = x0 * pw[o * 3] + x1 * pw[o * 3 + 1] + x2 * pw[o * 3 + 2] + pb[o];
  ln_relu8(v, g1, b1, t);
  mm8(t, w1, c1, u);
  ln_relu8(u, g2, b2, t);
  mm8(t, w2, c2, v);
  ln_relu8(v, g3, b3, t);
#pragma unroll
  for (int hh = 0; hh < 4; hh++) {
    float a = c3[hh];
#pragma unroll
    for (int i = 0; i < 8; i++) a += t[i] * w3[hh * 8 + i];
    pos_out[r * 4 + hh] = a * LOG2E;  // log2 domain for exp2-softmax
  }
}

// ---------------- K1: rpb frag expand + weight convert (fused) ----------------
// rpbf[(((hh*32+qg)*32 + jc)*64 + lane)*4 + r] = bias[q=qg*16+(lane&15)][j=jc*16+(lane>>4)*4+r]
__global__ void ca_rpbw(const float* __restrict__ pos, short* __restrict__ rpbf,
                        const float* __restrict__ qkv_w, const float* __restrict__ proj_w,
                        short* __restrict__ wq, short* __restrict__ wp) {
  const int blk = blockIdx.x;
  if (blk >= 1024) {
    int i = (blk - 1024) * 256 + threadIdx.x;  // 65536 threads
    if (i < 49152) {
      float f = qkv_w[i];
      if (i < 16384) f *= QSCALE;  // q rows: fold scale*log2e
      wq[i] = f2b(f);
    } else {
      wp[i - 49152] = f2b(proj_w[i - 49152]);
    }
    return;
  }
  int gid = blk * 256 + threadIdx.x;  // 262144 threads
  int lane = gid & 63, jc = (gid >> 6) & 31, qg = (gid >> 11) & 31, hh = gid >> 16;
  int q = qg * 16 + (lane & 15);
  int j0 = jc * 16 + (lane >> 4) * 4;
  bf16x4 outv;
#pragma unroll
  for (int r = 0; r < 4; r++) {
    int j = j0 + r;
    int rh = (q >> 6) - (j >> 6) + 7;
    int rw = ((q >> 3) & 7) - ((j >> 3) & 7) + 7;
    int rd = (q & 7) - (j & 7) + 7;
    int idx = (rh * 15 + rw) * 15 + rd;
    outv[r] = f2b(pos[idx * 4 + hh]);
  }
  *(bf16x4*)(rpbf + (size_t)gid * 4) = outv;
}

// ---------------- K2: QKV projection -> frag-order Q/K/V ----------------
// z=0: x -> qfrag; z=1: y -> kfrag + vfrag (V with PV j-permutation baked in)
__global__ __launch_bounds__(256) void ca_qkv(
    const float* __restrict__ x, const float* __restrict__ y,
    const short* __restrict__ wq, const float* __restrict__ qkv_b,
    short* __restrict__ gq, short* __restrict__ gk, short* __restrict__ gv) {
  __shared__ short lds[16384];  // 32KB: input stage (stride 136), then frag relayout
  const int z = blockIdx.y;
  const int t0 = blockIdx.x * 64;
  const int b_ = t0 >> 9;
  const int n0 = t0 & 511;
  const int tid = threadIdx.x;
  const float* __restrict__ in = (z == 0) ? x : y;
  // coalesced input staging: flat f32x4 per thread
#pragma unroll
  for (int i = 0; i < 8; i++) {
    int flat = i * 1024 + tid * 4;
    f32x4 f = *(const f32x4*)(in + (size_t)t0 * 128 + flat);
    int row = flat >> 7, col = flat & 127;
    bf16x4 hv;
#pragma unroll
    for (int e = 0; e < 4; e++) hv[e] = f2b(f[e]);
    *(bf16x4*)(lds + row * 136 + col) = hv;
  }
  __syncthreads();
  const int w = tid >> 6, lane = tid & 63, lr = lane & 15, lg = lane >> 4;
  bf16x8 afrag[4];
  {
    const short* ap = lds + (w * 16 + lr) * 136 + lg * 8;
#pragma unroll
    for (int k4 = 0; k4 < 4; k4++) afrag[k4] = *(const bf16x8*)(ap + k4 * 32);
  }
  __syncthreads();  // all afrag reads done before relayout overwrites lds

  const int nct = z ? 16 : 8;
  for (int ct = 0; ct < nct; ct++) {
    const int col = z * 128 + ct * 16;
    float bias = qkv_b[col + lr];
    if (z == 0) bias *= QSCALE;
    f32x4 acc = {bias, bias, bias, bias};
    const short* bp = wq + (size_t)(col + lr) * 128 + lg * 8;
#pragma unroll
    for (int k4 = 0; k4 < 4; k4++) {
      bf16x8 bfr = *(const bf16x8*)(bp + k4 * 32);
      acc = __builtin_amdgcn_mfma_f32_16x16x32_bf16(afrag[k4], bfr, acc, 0, 0, 0);
    }
    // acc[r] = out[token = t0 + w*16 + lg*4 + r][col + lr]
    if (z == 1 && ct >= 8) {
      // V frag (PV A-operand-compatible j-permuted layout):
      // region [hh(4)][ul(2)][dh(2)][lane(64)][e(8)]; lane_v = lane; e = (w&1)*4 + r
      const int hv_ = (ct - 8) >> 1;
      const int dh = (ct - 8) & 1;
      const int base = 8192 + (((hv_ * 2 + (w >> 1)) * 2 + dh) * 512) + lane * 8 + (w & 1) * 4;
      *(unsigned int*)(lds + base)     = pkbf(acc[0], acc[1]);
      *(unsigned int*)(lds + base + 2) = pkbf(acc[2], acc[3]);
    } else {  // Q or K: chunk (w*4 + ct>>1), lane=(n&15)+16*(d>>3), e=d&7
      const int d = (ct & 1) * 16 + lr;
      const int base = (w * 4 + (ct >> 1)) * 512 + 128 * (d >> 3) + (d & 7);
#pragma unroll
      for (int r = 0; r < 4; r++)
        lds[base + (lg * 4 + r) * 8] = f2b(acc[r]);
    }
  }
  __syncthreads();
  // cooperative 1KB-per-wave coalesced chunk stores
  if (z == 0) {
#pragma unroll
    for (int kk = 0; kk < 4; kk++) {
      const int c = kk * 4 + w, hh = c & 3, tg = c >> 2;
      bf16x8 vd = *(const bf16x8*)(lds + c * 512 + lane * 8);
      *(bf16x8*)(gq + (((size_t)b_ * 4 + hh) * 32 + (n0 >> 4) + tg) * 512 + lane * 8) = vd;
    }
  } else {
#pragma unroll
    for (int kk = 0; kk < 4; kk++) {
      const int c = kk * 4 + w, hh = c & 3, tg = c >> 2;
      bf16x8 vd = *(const bf16x8*)(lds + c * 512 + lane * 8);
      *(bf16x8*)(gk + (((size_t)b_ * 4 + hh) * 32 + (n0 >> 4) + tg) * 512 + lane * 8) = vd;
    }
#pragma unroll
    for (int kk = 0; kk < 4; kk++) {
      const int c = kk * 4 + w, hh = c >> 2, ul = (c >> 1) & 1, dh = c & 1;
      bf16x8 vd = *(const bf16x8*)(lds + 8192 + c * 512 + lane * 8);
      *(bf16x8*)(gv + ((((size_t)b_ * 4 + hh) * 16 + (n0 >> 5) + ul) * 2 + dh) * 512 + lane * 8) = vd;
    }
  }
}

// ---------------- K3: fused attention (2 q-groups per wave) ----------------
DEV void stage_kv(const short* kg, const short* vg, short* buf, int T, int w, int lane) {
#pragma unroll
  for (int i = 0; i < 4; i++) {
    const int c = w * 4 + i;
    const short* src;
    short* dst;
    if (c < 8) {
      src = kg + ((size_t)(T * 8 + c)) * 512 + lane * 8;
      dst = buf + c * 512;
    } else {
      src = vg + ((size_t)(T * 8 + c - 8)) * 512 + lane * 8;
      dst = buf + 4096 + (c - 8) * 512;
    }
    __builtin_amdgcn_global_load_lds((const __attribute__((address_space(1))) void*)src,
                                     (__attribute__((address_space(3))) void*)dst, 16, 0, 0);
  }
}

__global__ __launch_bounds__(256, 4) void ca_attn(
    const short* __restrict__ qfrag, const short* __restrict__ kfrag,
    const short* __restrict__ vfrag, const short* __restrict__ rpbf,
    short* __restrict__ aob) {
  __shared__ short kv[2][8192];  // dbuf: K tile 8KB | V tile 8KB (per buf 16KB)
  const int bid = blockIdx.x;
  // XCD swizzle: the 4 qt2-blocks of one (b,h) share bid%256 -> same XCD slot
  const int qt2 = bid >> 8, rem = bid & 255;
  const int b_ = rem >> 2, hh = rem & 3;
  const int bh = b_ * 4 + hh;
  const int tid = threadIdx.x;
  const int w = tid >> 6, lane = tid & 63, lg = lane >> 4;
  const int qg0 = qt2 * 8 + w, qg1 = qg0 + 4;  // two q-groups per wave
  const int q0 = qg0 * 16;

  const short* kg = kfrag + (size_t)bh * 16384;
  const short* vg = vfrag + (size_t)bh * 16384;
  const bf16x8 qf0 = *(const bf16x8*)(qfrag + ((size_t)bh * 32 + qg0) * 512 + lane * 8);
  const bf16x8 qf1 = *(const bf16x8*)(qfrag + ((size_t)bh * 32 + qg1) * 512 + lane * 8);
  const short* bp0 = rpbf + ((size_t)(hh * 32 + qg0) << 13) + lane * 4;
  const short* bp1 = rpbf + ((size_t)(hh * 32 + qg1) << 13) + lane * 4;

  union PU { bf16x8 v; unsigned int u[4]; };
  PU ones;
  ones.u[0] = 0x3F803F80u; ones.u[1] = 0x3F803F80u;
  ones.u[2] = 0x3F803F80u; ones.u[3] = 0x3F803F80u;

  stage_kv(kg, vg, &kv[0][0], 0, w, lane);
  __syncthreads();

  f32x4 a0 = {0.f, 0.f, 0.f, 0.f}, a1 = {0.f, 0.f, 0.f, 0.f}, a2 = {0.f, 0.f, 0.f, 0.f};
  f32x4 b0 = {0.f, 0.f, 0.f, 0.f}, b1 = {0.f, 0.f, 0.f, 0.f}, b2 = {0.f, 0.f, 0.f, 0.f};

  for (int T = 0; T < 4; T++) {
    const int cur = T & 1;
    if (T < 3) stage_kv(kg, vg, &kv[cur ^ 1][0], T + 1, w, lane);
    const short* kt = &kv[cur][0];
    const short* vt = &kv[cur][4096];

    u32x2 bw0[8], bw1[8];
#pragma unroll
    for (int t = 0; t < 8; t++) {
      bw0[t] = *(const u32x2*)(bp0 + (size_t)(T * 8 + t) * 256);
      bw1[t] = *(const u32x2*)(bp1 + (size_t)(T * 8 + t) * 256);
    }

#pragma unroll
    for (int uu = 0; uu < 4; uu++) {
      PU p0, p1;
#pragma unroll
      for (int half = 0; half < 2; half++) {
        const int t = uu * 2 + half;
        bf16x8 kf = *(const bf16x8*)(kt + t * 512 + lane * 8);
        f32x4 c0, c1;
        c0[0] = b2f(bw0[t].x << 16);
        c0[1] = b2f(bw0[t].x & 0xFFFF0000u);
        c0[2] = b2f(bw0[t].y << 16);
        c0[3] = b2f(bw0[t].y & 0xFFFF0000u);
        c1[0] = b2f(bw1[t].x << 16);
        c1[1] = b2f(bw1[t].x & 0xFFFF0000u);
        c1[2] = b2f(bw1[t].y << 16);
        c1[3] = b2f(bw1[t].y & 0xFFFF0000u);
        f32x4 s0 = __builtin_amdgcn_mfma_f32_16x16x32_bf16(kf, qf0, c0, 0, 0, 0);
        f32x4 s1 = __builtin_amdgcn_mfma_f32_16x16x32_bf16(kf, qf1, c1, 0, 0, 0);
        // no-max softmax: scores bounded (|s| < ~1), exp2 direct is exact-ratio
        p0.u[half * 2 + 0] = pkbf(__builtin_exp2f(s0[0]), __builtin_exp2f(s0[1]));
        p0.u[half * 2 + 1] = pkbf(__builtin_exp2f(s0[2]), __builtin_exp2f(s0[3]));
        p1.u[half * 2 + 0] = pkbf(__builtin_exp2f(s1[0]), __builtin_exp2f(s1[1]));
        p1.u[half * 2 + 1] = pkbf(__builtin_exp2f(s1[2]), __builtin_exp2f(s1[3]));
      }
      bf16x8 vf0 = *(const bf16x8*)(vt + (uu * 2 + 0) * 512 + lane * 8);
      bf16x8 vf1 = *(const bf16x8*)(vt + (uu * 2 + 1) * 512 + lane * 8);
      __builtin_amdgcn_s_setprio(1);
      a0 = __builtin_amdgcn_mfma_f32_16x16x32_bf16(p0.v, vf0, a0, 0, 0, 0);
      a1 = __builtin_amdgcn_mfma_f32_16x16x32_bf16(p0.v, vf1, a1, 0, 0, 0);
      a2 = __builtin_amdgcn_mfma_f32_16x16x32_bf16(p0.v, ones.v, a2, 0, 0, 0);
      b0 = __builtin_amdgcn_mfma_f32_16x16x32_bf16(p1.v, vf0, b0, 0, 0, 0);
      b1 = __builtin_amdgcn_mfma_f32_16x16x32_bf16(p1.v, vf1, b1, 0, 0, 0);
      b2 = __builtin_amdgcn_mfma_f32_16x16x32_bf16(p1.v, ones.v, b2, 0, 0, 0);
      __builtin_amdgcn_s_setprio(0);
    }
    if (T < 3) __syncthreads();
  }

  // epilogue: a2/b2[r] = row-sum for q = lg*4+r; normalize + transpose via LDS
  // kv[0] is dead here (last tile used kv[1]); wave-private regions
  const int lr = lane & 15;
  short* pt0 = &kv[0][(w * 2 + 0) * 1024];
  short* pt1 = &kv[0][(w * 2 + 1) * 1024];
#pragma unroll
  for (int r = 0; r < 4; r++) {
    float iv = 1.0f / a2[r];
    pt0[(lg * 4 + r) * 40 + lr] = f2b(a0[r] * iv);
    pt0[(lg * 4 + r) * 40 + 16 + lr] = f2b(a1[r] * iv);
    float jv = 1.0f / b2[r];
    pt1[(lg * 4 + r) * 40 + lr] = f2b(b0[r] * jv);
    pt1[(lg * 4 + r) * 40 + 16 + lr] = f2b(b1[r] * jv);
  }
  asm volatile("s_waitcnt lgkmcnt(0)" ::: "memory");
  __builtin_amdgcn_sched_barrier(0);
  {
    const int qq = lane >> 2, pp = lane & 3;
    bf16x8 od0 = *(const bf16x8*)(pt0 + qq * 40 + pp * 8);
    bf16x8 od1 = *(const bf16x8*)(pt1 + qq * 40 + pp * 8);
    *(bf16x8*)(aob + ((size_t)bh * 512 + q0 + qq) * 32 + pp * 8) = od0;
    *(bf16x8*)(aob + ((size_t)bh * 512 + q0 + 64 + qq) * 32 + pp * 8) = od1;
  }
}

// ---------------- K4: output projection ----------------
__global__ __launch_bounds__(256) void ca_proj(
    const short* __restrict__ aob, const short* __restrict__ wp,
    const float* __restrict__ proj_b, float* __restrict__ out) {
  const int t0 = blockIdx.x * 64;
  const int b_ = t0 >> 9, n0 = t0 & 511;
  const int tid = threadIdx.x;
  const int w = tid >> 6, lane = tid & 63, lr = lane & 15, lg = lane >> 4;
  bf16x8 afrag[4];
#pragma unroll
  for (int k4 = 0; k4 < 4; k4++)
    afrag[k4] = *(const bf16x8*)(aob + (((size_t)b_ * 4 + k4) * 512 + n0 + w * 16 + lr) * 32 + lg * 8);
#pragma unroll
  for (int ct = 0; ct < 8; ct++) {
    float bias = proj_b[ct * 16 + lr];
    f32x4 acc = {bias, bias, bias, bias};
    const short* bp = wp + (size_t)(ct * 16 + lr) * 128 + lg * 8;
#pragma unroll
    for (int k4 = 0; k4 < 4; k4++) {
      bf16x8 bfr = *(const bf16x8*)(bp + k4 * 32);
      acc = __builtin_amdgcn_mfma_f32_16x16x32_bf16(afrag[k4], bfr, acc, 0, 0, 0);
    }
#pragma unroll
    for (int r = 0; r < 4; r++)
      out[(size_t)(t0 + w * 16 + lg * 4 + r) * 128 + ct * 16 + lr] = acc[r];
  }
}

extern "C" void kernel_launch(void* const* d_in, const int* in_sizes, int n_in,
                              void* d_out, int out_size, void* d_ws, size_t ws_size,
                              hipStream_t stream) {
  const float* x      = (const float*)d_in[0];
  const float* y      = (const float*)d_in[1];
  const float* qkv_w  = (const float*)d_in[5];
  const float* qkv_b  = (const float*)d_in[6];
  const float* proj_w = (const float*)d_in[7];
  const float* proj_b = (const float*)d_in[8];
  const float* pos_w  = (const float*)d_in[9];
  const float* pos_b  = (const float*)d_in[10];
  const float* ln1g = (const float*)d_in[11];
  const float* ln1b = (const float*)d_in[12];
  const float* p1w  = (const float*)d_in[13];
  const float* p1b  = (const float*)d_in[14];
  const float* ln2g = (const float*)d_in[15];
  const float* ln2b = (const float*)d_in[16];
  const float* p2w  = (const float*)d_in[17];
  const float* p2b  = (const float*)d_in[18];
  const float* ln3g = (const float*)d_in[19];
  const float* ln3b = (const float*)d_in[20];
  const float* p3w  = (const float*)d_in[21];
  const float* p3b  = (const float*)d_in[22];
  float* out = (float*)d_out;

  char* ws = (char*)d_ws;
  short* gq    = (short*)(ws + OFF_Q);
  short* gk    = (short*)(ws + OFF_K);
  short* gv    = (short*)(ws + OFF_V);
  short* rpbf  = (short*)(ws + OFF_RPB);
  short* aob   = (short*)(ws + OFF_AO);
  float* posb  = (float*)(ws + OFF_POS);
  short* wq    = (short*)(ws + OFF_WQ);
  short* wp    = (short*)(ws + OFF_WP);

  ca_posmlp<<<14, 256, 0, stream>>>(pos_w, pos_b, ln1g, ln1b, p1w, p1b,
                                    ln2g, ln2b, p2w, p2b, ln3g, ln3b, p3w, p3b, posb);
  ca_rpbw<<<1280, 256, 0, stream>>>(posb, rpbf, qkv_w, proj_w, wq, wp);
  ca_qkv<<<dim3(512, 2), 256, 0, stream>>>(x, y, wq, qkv_b, gq, gk, gv);
  ca_attn<<<1024, 256, 0, stream>>>(gq, gk, gv, rpbf, aob);
  ca_proj<<<512, 256, 0, stream>>>(aob, wp, proj_b, out);
}